// Round 2
// baseline (75893.756 us; speedup 1.0000x reference)
//
#include <hip/hip_runtime.h>

// LIF scan: B=16, S=256, H=128, N=64. T = S*H = 32768 sequential steps per
// (b,n) chain; 1024 chains. Bit-exactness with the numpy fp32 sequential
// reference is required (hard thresholds on sequentially-rounded sums).
//
// Key empirical fact (R1): spikes fire every ~3 steps (x~N(0,1), th~U(0,1)),
// so outputs are ~30% dense and the R1 in-loop scattered stores (64 cache
// lines per store, ~128 lines/step) dominated at 168 cyc/step.
//
// Architecture:
//   Phase 1: chains emit ONLY the per-step 64-lane spike ballot (4 MB masks
//            in d_ws) — the minimal sequential product. ~8-12 cyc/step.
//   Phase 2: dense, coalesced expansion. Out-value at spike t is bit-exactly
//            recomputable: acc resets to exactly 0, so value = sequential
//            fp32 sum of x over the segment since the previous spike bit.

namespace {
constexpr int kB = 16;
constexpr int kS = 256;
constexpr int kH = 128;
constexpr int kN = 64;
constexpr int kT = kS * kH;                  // 32768
constexpr long kPerB = (long)kS * kN * kH;   // 2,097,152
constexpr size_t kMaskBytes = (size_t)kB * kT * 8;  // 4 MB
}

// ---------------------------------------------------------------------------
// Phase 1: sequential chains -> spike ballots. block = batch, lane = neuron.
// Critical path per step: {v_add, v_cmp} (parallel off s) -> v_cndmask = 8 cyc.
// s' = prev ? x : fl(s + x) is bit-equivalent to fl(acc + x) with reset
// (zeros never spike; sign-of-zero washes out at first nonzero add) — proven
// by R1's absmax = 0.
// ---------------------------------------------------------------------------
__global__ __launch_bounds__(64) void lif_mask_kernel(
    const float* __restrict__ x, const float* __restrict__ thresh,
    const float* __restrict__ acc0, unsigned long long* __restrict__ masks) {
  const int b = blockIdx.x;
  const int lane = threadIdx.x;
  const float th = thresh[lane];
  const float* __restrict__ xb = x + b * kT;
  unsigned long long* __restrict__ mb = masks + (long)b * kT;
  __shared__ unsigned long long lm[64];

  float s = acc0[b * kN + lane];
  bool prev = false;

  for (int t0 = 0; t0 < kT; t0 += 64) {
#pragma unroll
    for (int k = 0; k < 64; ++k) {
      const float xt = xb[t0 + k];   // wave-uniform -> s_load broadcast
      const float u = s + xt;        // fl(s + x)
      s = prev ? xt : u;             // reset-speculation form
      prev = s > th;
      const unsigned long long m = __ballot(prev);  // SALU read of vcc
      if (lane == 0) lm[k] = m;      // one ds_write, no global traffic
    }
    __syncthreads();                 // single wave: near-free
    mb[t0 + lane] = lm[lane];        // coalesced 512 B flush
    __syncthreads();
  }
}

// ---------------------------------------------------------------------------
// Phase 2: dense expansion. block = (b, s) row; 256 threads; writes the
// 8192-elem outs row + 8192-elem spikes row fully coalesced (64 KB/block).
// Value at spike t = acc0-or-0 + sequential fp32 adds of x since previous
// spike bit (avg segment ~3; cross-row backscan reads masks/x globally, rare).
// ---------------------------------------------------------------------------
__global__ __launch_bounds__(256) void lif_expand_kernel(
    const float* __restrict__ x, const float* __restrict__ acc0,
    const unsigned long long* __restrict__ masks, float* __restrict__ out) {
  const int b = blockIdx.x >> 8;
  const int s = blockIdx.x & 255;
  const int row0 = s << 7;           // first t of this row
  const int tid = threadIdx.x;

  __shared__ float xrow[128];
  __shared__ unsigned long long mrow[128];

  const float* __restrict__ gx = x + (long)b * kT;
  const unsigned long long* __restrict__ gm = masks + (long)b * kT;

  if (tid < 128) xrow[tid] = gx[row0 + tid];
  else mrow[tid - 128] = gm[row0 + (tid - 128)];
  __syncthreads();

  float* __restrict__ outs_b = out + (long)b * kPerB + (long)row0 * kN;
  float* __restrict__ spks_b = outs_b + (long)kB * kPerB;

#pragma unroll 4
  for (int c = 0; c < 32; ++c) {
    const int pos = (c << 8) + tid;  // 0..8191 within the row, = n*128 + h
    const int n = pos >> 7;
    const int h = pos & 127;
    const unsigned long long bitn = 1ULL << n;

    float ov = 0.f, sv = 0.f;
    if (mrow[h] & bitn) {
      sv = 1.f;
      // backscan to previous spike of chain n
      int j = h - 1;
      while (j >= 0 && !(mrow[j] & bitn)) --j;
      float v;
      if (j >= 0) {
        v = 0.f;
        for (int k = j + 1; k <= h; ++k) v += xrow[k];   // exact seq. order
      } else {
        // segment crosses the row start: global backscan (rare, ~2% threads)
        int tt = row0 - 1;
        while (tt >= 0 && !(gm[tt] & bitn)) --tt;
        v = (tt < 0) ? acc0[b * kN + n] : 0.f;
        for (int k = tt + 1; k < row0; ++k) v += gx[k];
        for (int k = 0; k <= h; ++k) v += xrow[k];
      }
      ov = v;
    }
    outs_b[pos] = ov;   // coalesced 1 KB per wave-iteration
    spks_b[pos] = sv;
  }
}

// ---------------------------------------------------------------------------
// Fallback (ws too small): R1's passing version — zero-fill + direct stores.
// ---------------------------------------------------------------------------
__global__ __launch_bounds__(256) void fill_zero_kernel(float4* __restrict__ out,
                                                        int n4) {
  int i = blockIdx.x * 256 + threadIdx.x;
  const int stride = gridDim.x * 256;
  const float4 z = make_float4(0.f, 0.f, 0.f, 0.f);
  for (; i < n4; i += stride) out[i] = z;
}

__global__ __launch_bounds__(64) void lif_sim_direct_kernel(
    const float* __restrict__ x, const float* __restrict__ thresh,
    const float* __restrict__ acc0, float* __restrict__ out) {
  const int b = blockIdx.x;
  const int n = threadIdx.x;
  const float th = thresh[n];
  const float* __restrict__ xb = x + b * kT;
  float* __restrict__ outs_b = out + (long)b * kPerB;
  float* __restrict__ spks_b = out + (long)(kB + b) * kPerB;
  float s = acc0[b * kN + n];
  bool prev = false;
#pragma unroll 8
  for (int t = 0; t < kT; ++t) {
    const float xt = xb[t];
    const float u = s + xt;
    s = prev ? xt : u;
    prev = s > th;
    if (prev) {
      const int idx = (t >> 7) * (kN * kH) + n * kH + (t & 127);
      outs_b[idx] = s;
      spks_b[idx] = 1.0f;
    }
  }
}

// ---------------------------------------------------------------------------
extern "C" void kernel_launch(void* const* d_in, const int* in_sizes, int n_in,
                              void* d_out, int out_size, void* d_ws, size_t ws_size,
                              hipStream_t stream) {
  const float* inputs = (const float*)d_in[0];    // [B,S,H] fp32
  const float* threshes = (const float*)d_in[1];  // [N] fp32
  const float* acc0 = (const float*)d_in[2];      // [B,N] fp32
  float* out = (float*)d_out;

  if (ws_size >= kMaskBytes) {
    unsigned long long* masks = (unsigned long long*)d_ws;
    // Phase 1: 16 sequential chains-waves -> 4 MB spike masks.
    lif_mask_kernel<<<kB, kN, 0, stream>>>(inputs, threshes, acc0, masks);
    // Phase 2: dense coalesced expansion, 4096 blocks (writes every element).
    lif_expand_kernel<<<kB * kS, 256, 0, stream>>>(inputs, acc0, masks, out);
  } else {
    const int n4 = out_size / 4;
    fill_zero_kernel<<<8192, 256, 0, stream>>>((float4*)out, n4);
    lif_sim_direct_kernel<<<kB, kN, 0, stream>>>(inputs, threshes, acc0, out);
  }
}

// Round 3
// 2131.088 us; speedup vs baseline: 35.6127x; 35.6127x over previous
//
#include <hip/hip_runtime.h>

// LIF scan: B=16, S=256, H=128, N=64. T = S*H = 32768 sequential steps per
// (b,n) chain; 1024 chains. Bit-exactness with the numpy fp32 sequential
// reference is required (hard thresholds on sequentially-rounded sums), so
// the per-chain dependent add chain cannot be reassociated/parallelized.
//
// R1 post-mortem: direct-store sim was x-stream LATENCY-bound (168 cyc/step,
// VALUBusy ~0.15% -> vmcnt stalls), not store-bound. Spikes are sparse
// (WRITE_SIZE 5 MB -> <~1% density, heavy-tailed first-passage segments).
// R2 post-mortem: recomputing segment sums in a second pass is catastrophic
// (dependent global loads over heavy-tailed segments -> 110 ms stragglers).
//
// R3 architecture:
//   1) fill_zero: 268 MB dense zeros (pure BW, ~50 us).
//   2) lif_sim:   16 blocks x 64 lanes (block=batch, lane=neuron), x stream
//      double-buffered in registers (2 x 16 float4, uniform-address dwordx4
//      loads, >=64-step in-flight slack), rare exec-masked scattered stores
//      straight into the zeroed output. Chain: v_add || v_cmp -> v_cndmask
//      ~ 8 cyc/step -> ~110 us floor.

namespace {
constexpr int kB = 16;
constexpr int kS = 256;
constexpr int kH = 128;
constexpr int kN = 64;
constexpr int kT = kS * kH;                 // 32768 steps per chain
constexpr long kPerB = (long)kS * kN * kH;  // 2,097,152 elems per batch per tensor
}

typedef float v4f __attribute__((ext_vector_type(4)));

// ---------------------------------------------------------------------------
// Kernel 1: zero-fill outs + spikes (268 MB). Wave writes 1 KB contiguous per
// instruction (full lines, no RFO); nontemporal hint to avoid polluting L2.
// ---------------------------------------------------------------------------
__global__ __launch_bounds__(256) void fill_zero_kernel(v4f* __restrict__ out,
                                                        int n4) {
  int i = blockIdx.x * 256 + threadIdx.x;
  const int stride = gridDim.x * 256;
  const v4f z = {0.f, 0.f, 0.f, 0.f};
  for (; i < n4; i += stride) __builtin_nontemporal_store(z, &out[i]);
}

// ---------------------------------------------------------------------------
// Kernel 2: the 1024 sequential chains. block = batch b, lane = neuron n.
//
// State trick (proven bit-exact in R1, absmax=0):
//   s' = prev ? x : fl(s + x)  ==  fl(acc + x) with reset-to-0,
// putting only {v_add -> v_cndmask} on the dependent chain (v_cmp overlaps).
//
// x supply: x[b][t] is wave-uniform. One S-row (128 steps) per outer
// iteration from two 16xfloat4 register buffers; each buffer is refilled
// immediately after its 64-step consume -> loads stay in flight ~600 cyc
// while the next half-row computes (x is L2-warm across graph replays).
//
// Stores: spike steps are rare; exec-masked branch, address = per-lane base
// + literal offset (t&127 is a compile-time constant inside the row).
// ---------------------------------------------------------------------------
__global__ __launch_bounds__(64) void lif_sim_kernel(
    const float* __restrict__ x, const float* __restrict__ thresh,
    const float* __restrict__ acc0, float* __restrict__ out) {
  const int b = blockIdx.x;
  const int n = threadIdx.x;
  const float th = thresh[n];
  const v4f* __restrict__ xb4 = (const v4f*)(x + (long)b * kT);

  // outs[b][row][n][0..127]: per-lane base advances 8192 floats per row.
  float* __restrict__ outs_p = out + (long)b * kPerB + (long)n * kH;
  float* __restrict__ spks_p = outs_p + (long)kB * kPerB;

  float s = acc0[b * kN + n];
  bool prev = false;

  v4f bufA[16], bufB[16];
#pragma unroll
  for (int i = 0; i < 16; ++i) bufA[i] = xb4[i];
#pragma unroll
  for (int i = 0; i < 16; ++i) bufB[i] = xb4[16 + i];

  for (int row = 0; row < kS; ++row) {
    const v4f* __restrict__ nxt = xb4 + (row + 1) * 32;  // next row's 32 f4

    // ---- steps k = 0..63 from bufA ----
#pragma unroll
    for (int k = 0; k < 64; ++k) {
      const float xt = bufA[k >> 2][k & 3];  // static reg, wave-uniform value
      const float u = s + xt;                // fl(s + x), on critical path
      s = prev ? xt : u;                     // reset-speculation select
      prev = s > th;                         // off-chain, overlaps next add
      if (prev) {                            // rare; exec-masked
        outs_p[k] = s;
        spks_p[k] = 1.0f;
      }
    }
    // refill bufA with next row's first half (in flight during bufB consume)
    if (row + 1 < kS) {
#pragma unroll
      for (int i = 0; i < 16; ++i) bufA[i] = nxt[i];
    }

    // ---- steps k = 64..127 from bufB ----
#pragma unroll
    for (int k = 0; k < 64; ++k) {
      const float xt = bufB[k >> 2][k & 3];
      const float u = s + xt;
      s = prev ? xt : u;
      prev = s > th;
      if (prev) {
        outs_p[64 + k] = s;
        spks_p[64 + k] = 1.0f;
      }
    }
    if (row + 1 < kS) {
#pragma unroll
      for (int i = 0; i < 16; ++i) bufB[i] = nxt[16 + i];
    }

    outs_p += kN * kH;  // next row: +8192 floats
    spks_p += kN * kH;
  }
}

// ---------------------------------------------------------------------------
extern "C" void kernel_launch(void* const* d_in, const int* in_sizes, int n_in,
                              void* d_out, int out_size, void* d_ws, size_t ws_size,
                              hipStream_t stream) {
  const float* inputs = (const float*)d_in[0];    // [B,S,H] fp32
  const float* threshes = (const float*)d_in[1];  // [N] fp32
  const float* acc0 = (const float*)d_in[2];      // [B,N] fp32
  float* out = (float*)d_out;

  // 1) dense zero-fill (every non-spike element is exactly 0).
  const int n4 = out_size / 4;  // 16,777,216 float4
  fill_zero_kernel<<<4096, 256, 0, stream>>>((v4f*)out, n4);

  // 2) sequential chains with register-pipelined x stream; rare scattered
  //    spike stores land on the zeroed output (same stream -> ordered).
  lif_sim_kernel<<<kB, kN, 0, stream>>>(inputs, threshes, acc0, out);
}

// Round 4
// 1059.906 us; speedup vs baseline: 71.6042x; 2.0106x over previous
//
#include <hip/hip_runtime.h>

// LIF scan: B=16, S=256, H=128, N=64. T = S*H = 32768 sequential steps per
// (b,n) chain; 1024 independent chains. Bit-exactness with the numpy fp32
// sequential reference required -> the per-chain add chain cannot be
// reassociated. Chain form (proven bit-exact in R1/R3, absmax=0):
//     s' = prev ? x : fl(s + x);  prev' = s' > th
//
// R3 post-mortem: 134 cyc/step. x supply was already scalarized (VGPR=8,
// SGPR=112 -> SGPR x buffers), so the cost was the PER-STEP DIVERGENT BRANCH:
// lanes with tiny thresholds spike ~every 2 steps, so P(any-lane-spikes) ~ 1;
// every step paid saveexec + taken-branch bubbles + 2 scattered store issues
// + conservative vmcnt coupling. VALU itself was only ~12 cyc/step.
//
// R4: one fused kernel, producer/consumer waves, NO branches, NO scattered
// stores, NO fill pass:
//   wave 0 (compute): 4-instr step: v_add || v_cmp -> v_cndmask -> ds_write
//     (raw s staged to LDS, lanes stride-1 = conflict-free). 
//   wave 1 (flush):   drains the previous row from double-buffered LDS,
//     derives out = s>th ? s : 0 and spike = s>th ? 1 : 0 (same comparison,
//     same s -> bit-identical), writes both tensors as coalesced float4.
// Dense writes -> every output element written exactly once -> no zero-fill.
// 64 blocks = (batch, 16-neuron group); lanes 16..63 of the compute wave
// redundantly replicate chains 0..15 (harmless; flush reads slots 0..15).

namespace {
constexpr int kB = 16;
constexpr int kS = 256;
constexpr int kH = 128;
constexpr int kN = 64;
constexpr int kT = kS * kH;                 // 32768 steps per chain
constexpr long kPerB = (long)kS * kN * kH;  // 2,097,152 elems per batch per tensor
}

typedef float v4f __attribute__((ext_vector_type(4)));

__global__ __launch_bounds__(128) void lif_fused_kernel(
    const float* __restrict__ x, const float* __restrict__ thresh,
    const float* __restrict__ acc0, float* __restrict__ out) {
  const int bid = blockIdx.x;
  const int b = bid >> 2;        // batch
  const int ng = bid & 3;        // neuron group (16 chains)
  const int tid = threadIdx.x;   // 0..127
  const int wave = tid >> 6;     // 0 = compute, 1 = flush
  const int lane = tid & 63;

  // [parity][k][slot]; slot = writer lane (stride-1 across lanes -> 2-way,
  // free). Flush reads slots 0..15 (4-way on ds_read, hidden in flush wave).
  __shared__ float buf[2][kH][64];  // 64 KB

  const float* __restrict__ xb = x + (long)b * kT;
  float* __restrict__ outs_g = out + (long)b * kPerB + (long)(ng * 16) * kH;
  float* __restrict__ spks_g = outs_g + (long)kB * kPerB;

  if (wave == 0) {
    // ------------------- compute wave: the sequential chains ---------------
    const int n = lane & 15;                    // chain within group
    const float th = thresh[ng * 16 + n];
    float s = acc0[b * kN + ng * 16 + n];
    bool prev = false;

    for (int r = 0; r < kS + 1; ++r) {
      if (r < kS) {
        float* __restrict__ bk = &buf[r & 1][0][lane];
        const float* __restrict__ xr = xb + r * kH;
#pragma unroll
        for (int k = 0; k < kH; ++k) {
          const float xt = xr[k];   // wave-uniform -> SGPR via s_load
          const float u = s + xt;   // fl(s + x): dep-chain op 1
          s = prev ? xt : u;        // dep-chain op 2 (v_cndmask)
          prev = s > th;            // off-chain
          bk[k * 64] = s;           // ds_write_b32, imm offset k*256
        }
      }
      __syncthreads();  // row r visible to flush; flush of r-1 done
    }
  } else {
    // ------------------- flush wave: derive + coalesced store --------------
    const int n = lane >> 2;   // 0..15 chain slot
    const int hg = lane & 3;   // h sub-group
    const float th = thresh[ng * 16 + n];

    for (int r = 0; r < kS + 1; ++r) {
      if (r > 0) {
        const int rr = r - 1;
        const float(*bk)[64] = buf[rr & 1];
        float* __restrict__ orow = outs_g + (long)rr * (kN * kH) + n * kH;
        float* __restrict__ srow = spks_g + (long)rr * (kN * kH) + n * kH;
#pragma unroll
        for (int i = 0; i < 8; ++i) {
          const int h0 = hg * 4 + i * 16;
          v4f ov, sv;
#pragma unroll
          for (int j = 0; j < 4; ++j) {
            const float v = bk[h0 + j][n];      // staged s (bit-exact)
            const bool sp = v > th;             // same compare as reference
            ov[j] = sp ? v : 0.0f;
            sv[j] = sp ? 1.0f : 0.0f;
          }
          // lanes (n, hg) with hg fastest -> 16B-consecutive -> coalesced
          *(v4f*)(orow + h0) = ov;
          *(v4f*)(srow + h0) = sv;
        }
      }
      __syncthreads();
    }
  }
}

// ---------------------------------------------------------------------------
extern "C" void kernel_launch(void* const* d_in, const int* in_sizes, int n_in,
                              void* d_out, int out_size, void* d_ws, size_t ws_size,
                              hipStream_t stream) {
  const float* inputs = (const float*)d_in[0];    // [B,S,H] fp32
  const float* threshes = (const float*)d_in[1];  // [N] fp32
  const float* acc0 = (const float*)d_in[2];      // [B,N] fp32
  float* out = (float*)d_out;

  // 64 blocks = 16 batches x 4 neuron-groups; 2 waves (compute + flush).
  // Writes every output element -> no fill / memset needed.
  lif_fused_kernel<<<kB * 4, 128, 0, stream>>>(inputs, threshes, acc0, out);
}